// Round 9
// baseline (229.956 us; speedup 1.0000x reference)
//
#include <hip/hip_runtime.h>

// VectorQuantizer: x[128,512,64] f32, codebook[1024,64] f32
// outputs (flat in d_out, float32): quantized[4194304], loss[1], indices[65536]
//
// R9: kMF uses the m97-proven LDS pipeline: per code-tile, STAGE(next tile)
// via global_load_lds -> ds_read(current) -> 12 MFMA -> __syncthreads (drains
// the stage under the compute). Codebook stored TRANSPOSED by kC as
// cwT[tile][chunk][code][16B] so both the global_load_lds destination and all
// ds_read_b128 fragments are linear (lane*16) -> zero bank conflicts, no
// swizzle needed. B-frags transient -> no register-pipeline spills (R8: 74MB
// scratch; R7: 60-VGPR serialization).
// Exactness: fp32 top-2 gap screen (err <= ~2.4e-2 < TAU=0.05); flagged rows
// -> k3 fp32-exact sweep + selective fp64 -> argmin fp64-exact. Loss fp64,
// fixed order (deterministic).

typedef __attribute__((ext_vector_type(8))) short bf16x8;
typedef __attribute__((ext_vector_type(4))) float f32x4;
typedef __attribute__((ext_vector_type(8))) unsigned short u16x8;

static constexpr int Vn    = 1024;
static constexpr int Hn    = 64;
static constexpr int Nrows = 128 * 512;          // 65536
static constexpr int QSZ   = Nrows * Hn;         // 4194304
#define TAU 0.05f
#define MARGIN 4e-3f

__device__ inline unsigned short f2bf(float f) {         // RNE fp32->bf16
  unsigned u = __float_as_uint(f);
  return (unsigned short)((u + 0x7fffu + ((u >> 16) & 1u)) >> 16);
}
__device__ inline float bf2f(unsigned short h) {
  return __uint_as_float(((unsigned)h) << 16);
}

__device__ __forceinline__ void gload_lds16(const void* g, void* l) {
  __builtin_amdgcn_global_load_lds(
      (const __attribute__((address_space(1))) unsigned int*)g,
      (__attribute__((address_space(3))) unsigned int*)l, 16, 0, 0);
}
__device__ __forceinline__ void gload_lds4(const void* g, void* l) {
  __builtin_amdgcn_global_load_lds(
      (const __attribute__((address_space(1))) unsigned int*)g,
      (__attribute__((address_space(3))) unsigned int*)l, 4, 0, 0);
}

// ---- ws layout (bytes) ----
// 0      : double cnormd[1024]       (8192)
// 8192   : double partials[1024]     (8192; region reserves 32768)
// 40960  : float  cnormf[1024]       (4096)
// 45056  : int    bestIdx[65536]     (262144)
// 307200 : int    flagCount          (8)
// 307208 : int    flagList[65536]    (262144)
// 573440 : ushort cwT[64][16][16][8] (262144)  transposed: [tile][chunk][code][8u16]

// Codebook prep: thread = (code v, 16-elem segment). Coalesced float4 loads,
// 4-lane shfl_xor fp64 norm reduction; writes TRANSPOSED bf16 hi/lo chunks:
// chunk c (c<8: hi of elems [8c,8c+8); c>=8: lo of elems [8(c-8),..)) at
// cwT + tile*4096 + c*256 + (v&15)*16.
__global__ __launch_bounds__(256) void kC(
    const float* __restrict__ cb, unsigned short* __restrict__ cwT,
    double* __restrict__ cnd, float* __restrict__ cnf,
    int* __restrict__ flagCount) {
  const int t = blockIdx.x * 256 + threadIdx.x;  // 4096 threads
  if (t == 0) *flagCount = 0;
  const int v = t >> 2, seg = t & 3;
  const float4* src = reinterpret_cast<const float4*>(cb + v * Hn + seg * 16);
  float vals[16];
  double s = 0;
#pragma unroll
  for (int q = 0; q < 4; ++q) {
    float4 f = src[q];
    vals[q * 4 + 0] = f.x; vals[q * 4 + 1] = f.y;
    vals[q * 4 + 2] = f.z; vals[q * 4 + 3] = f.w;
    s += (double)f.x * f.x + (double)f.y * f.y +
         (double)f.z * f.z + (double)f.w * f.w;
  }
  s += __shfl_xor(s, 1);                         // 4-lane group reduce
  s += __shfl_xor(s, 2);
  if (seg == 0) { cnd[v] = s; cnf[v] = (float)s; }

  // scale by -2 is folded into x (A side); codebook stays plain bf16 split.
  u16x8 h0, h1, l0, l1;
#pragma unroll
  for (int j = 0; j < 8; ++j) {
    unsigned short h = f2bf(vals[j]);
    h0[j] = h; l0[j] = f2bf(vals[j] - bf2f(h));
    unsigned short h2 = f2bf(vals[8 + j]);
    h1[j] = h2; l1[j] = f2bf(vals[8 + j] - bf2f(h2));
  }
  char* base = (char*)cwT + (size_t)(v >> 4) * 4096 + (v & 15) * 16;
  *(u16x8*)(base + (2 * seg + 0) * 256) = h0;        // hi chunk 2seg
  *(u16x8*)(base + (2 * seg + 1) * 256) = h1;        // hi chunk 2seg+1
  *(u16x8*)(base + (8 + 2 * seg + 0) * 256) = l0;    // lo chunk 8+2seg
  *(u16x8*)(base + (8 + 2 * seg + 1) * 256) = l1;    // lo chunk 9+2seg
}

// Fused MFMA screen + argmin. Block = 4 waves, 32 rows (2 row-tiles); wave w
// sweeps codes [256w, 256w+256) as 16 code-tiles through a per-wave LDS
// double buffer (m97 2-barrier pipeline). Per tile: K=192 via 6 MFMA
// ((-2xh).ch + (-2xh).cl + (-2xl).ch), C-init = ||c||^2 -> acc = key.
// C frag: col=lane&15, row=4*(lane>>4)+reg (m89-verified; validated R4-R8).
__global__ __launch_bounds__(256, 4) void kMF(
    const float* __restrict__ x, const unsigned short* __restrict__ cwT,
    const float* __restrict__ cnf, int* __restrict__ bestIdx,
    int* __restrict__ flagCount, int* __restrict__ flagList,
    float* __restrict__ outIdx) {
  __shared__ __align__(16) char ldsTile[8][4096];  // [wave*2+sel][tile 4KB]
  __shared__ __align__(16) float ldsCnf[1024];     // [wave][256]
  __shared__ float sB1[4][32], sB2[4][32];
  __shared__ int   sI[4][32];

  const int tid = threadIdx.x;
  const int lane = tid & 63;
  const int w = tid >> 6;
  const int l15 = lane & 15, g = lane >> 4;
  const int rowBase = blockIdx.x * 32;
  const int codeBase = w * 256;
  const char* cwTb = (const char*)cwT;

  // ---- prologue: stage tile 0 + this wave's 256 cnf values ----
  {
    const char* gsrc = cwTb + (size_t)(w * 16) * 4096 + lane * 16;
    char* ldst = ldsTile[w * 2];
#pragma unroll
    for (int it = 0; it < 4; ++it)
      gload_lds16(gsrc + it * 1024, ldst + it * 1024);
    const char* gc = (const char*)(cnf + codeBase) + lane * 4;
    char* lc = (char*)&ldsCnf[w * 256];
#pragma unroll
    for (int it = 0; it < 4; ++it)
      gload_lds4(gc + it * 256, lc + it * 256);
  }

  // ---- A fragments: 2 row-tiles x {h0,h1,l0,l1} of (-2x) ----
  bf16x8 A[2][4];
#pragma unroll
  for (int rt = 0; rt < 2; ++rt) {
    const float* xr = x + (long)(rowBase + rt * 16 + l15) * Hn + g * 8;
    float4 fa0 = *(const float4*)(xr + 0);
    float4 fa1 = *(const float4*)(xr + 4);
    float4 fb0 = *(const float4*)(xr + 32);
    float4 fb1 = *(const float4*)(xr + 36);
    float va[8] = {fa0.x, fa0.y, fa0.z, fa0.w, fa1.x, fa1.y, fa1.z, fa1.w};
    float vb[8] = {fb0.x, fb0.y, fb0.z, fb0.w, fb1.x, fb1.y, fb1.z, fb1.w};
    bf16x8 h0, h1, l0, l1;
#pragma unroll
    for (int j = 0; j < 8; ++j) {
      float sa = -2.0f * va[j];
      unsigned short h = f2bf(sa);
      h0[j] = (short)h;
      l0[j] = (short)f2bf(sa - bf2f(h));
      float sb = -2.0f * vb[j];
      unsigned short h2 = f2bf(sb);
      h1[j] = (short)h2;
      l1[j] = (short)f2bf(sb - bf2f(h2));
    }
    A[rt][0] = h0; A[rt][1] = h1; A[rt][2] = l0; A[rt][3] = l1;
  }

  float b1[2][4], b2[2][4];
  int   bi[2][4];
#pragma unroll
  for (int rt = 0; rt < 2; ++rt)
#pragma unroll
    for (int r = 0; r < 4; ++r) { b1[rt][r] = 3.4e38f; b2[rt][r] = 3.4e38f; bi[rt][r] = 0; }

  __syncthreads();                               // tile 0 + cnf staged

  // ---- main loop: STAGE(next) || compute(cur), barrier drains stage ----
  for (int ct = 0; ct < 16; ++ct) {
    const int sel = ct & 1;
    if (ct < 15) {                               // stage next tile first
      const char* gsrc = cwTb + (size_t)(w * 16 + ct + 1) * 4096 + lane * 16;
      char* ldst = ldsTile[w * 2 + (sel ^ 1)];
#pragma unroll
      for (int it = 0; it < 4; ++it)
        gload_lds16(gsrc + it * 1024, ldst + it * 1024);
    }

    const char* lb = ldsTile[w * 2 + sel] + lane * 16;   // linear: lane*16
    bf16x8 B0 = *(const bf16x8*)(lb + 0);        // ch k[8g..8g+8)
    bf16x8 B1 = *(const bf16x8*)(lb + 1024);     // ch k[32+8g..)
    bf16x8 B2 = *(const bf16x8*)(lb + 2048);     // cl k[8g..)
    bf16x8 B3 = *(const bf16x8*)(lb + 3072);     // cl k[32+8g..)
    const float cnfv = ldsCnf[w * 256 + ct * 16 + l15];
    const int v = codeBase + ct * 16 + l15;

#pragma unroll
    for (int rt = 0; rt < 2; ++rt) {
      f32x4 acc = {cnfv, cnfv, cnfv, cnfv};      // C-init = ||c||^2
      acc = __builtin_amdgcn_mfma_f32_16x16x32_bf16(A[rt][0], B0, acc, 0, 0, 0);
      acc = __builtin_amdgcn_mfma_f32_16x16x32_bf16(A[rt][1], B1, acc, 0, 0, 0);
      acc = __builtin_amdgcn_mfma_f32_16x16x32_bf16(A[rt][0], B2, acc, 0, 0, 0);
      acc = __builtin_amdgcn_mfma_f32_16x16x32_bf16(A[rt][1], B3, acc, 0, 0, 0);
      acc = __builtin_amdgcn_mfma_f32_16x16x32_bf16(A[rt][2], B0, acc, 0, 0, 0);
      acc = __builtin_amdgcn_mfma_f32_16x16x32_bf16(A[rt][3], B1, acc, 0, 0, 0);
#pragma unroll
      for (int r = 0; r < 4; ++r) {
        float key = acc[r];                      // = ||c||^2 - 2 x.c
        bool lt = key < b1[rt][r];
        b2[rt][r] = __builtin_amdgcn_fmed3f(key, b1[rt][r], b2[rt][r]); // 2nd-best
        b1[rt][r] = fminf(b1[rt][r], key);
        bi[rt][r] = lt ? v : bi[rt][r];
      }
    }
    __syncthreads();                             // drain stage under compute
  }

  // ---- merge top-2 across the 16 lanes holding each row ----
#pragma unroll
  for (int rt = 0; rt < 2; ++rt)
#pragma unroll
    for (int r = 0; r < 4; ++r) {
      float B1r = b1[rt][r], B2r = b2[rt][r];
      int Ir = bi[rt][r];
#pragma unroll
      for (int m = 1; m < 16; m <<= 1) {
        float o1 = __shfl_xor(B1r, m), o2 = __shfl_xor(B2r, m);
        int oi = __shfl_xor(Ir, m);
        float worse = fmaxf(B1r, o1);
        B2r = fminf(fminf(B2r, o2), worse);
        bool take = (o1 < B1r) || (o1 == B1r && oi < Ir);
        B1r = take ? o1 : B1r;
        Ir  = take ? oi : Ir;
      }
      b1[rt][r] = B1r; b2[rt][r] = B2r; bi[rt][r] = Ir;
    }

  // Writers: lane with l15==r publishes row rt*16 + 4g + r (static reg idx).
#pragma unroll
  for (int rt = 0; rt < 2; ++rt)
#pragma unroll
    for (int r = 0; r < 4; ++r)
      if (l15 == r) {
        int rowIn = rt * 16 + 4 * g + r;
        sB1[w][rowIn] = b1[rt][r];
        sB2[w][rowIn] = b2[rt][r];
        sI[w][rowIn]  = bi[rt][r];
      }
  __syncthreads();

  if (tid < 32) {
    float B1 = sB1[0][tid], B2 = sB2[0][tid];
    int I = sI[0][tid];
#pragma unroll
    for (int ww = 1; ww < 4; ++ww) {
      float o1 = sB1[ww][tid], o2 = sB2[ww][tid];
      int oi = sI[ww][tid];
      float worse = fmaxf(B1, o1);
      B2 = fminf(fminf(B2, o2), worse);
      bool take = (o1 < B1) || (o1 == B1 && oi < I);
      B1 = take ? o1 : B1;
      I  = take ? oi : I;
    }
    const int row = rowBase + tid;
    bestIdx[row] = I;
    outIdx[row] = (float)I;
    if (B2 - B1 <= TAU) {
      int slot = atomicAdd(flagCount, 1);
      flagList[slot] = row;                      // order-independent use
    }
  }
}

// Recheck flagged rows: exact-fp32 sweep of all 1024 codes, then fp64 keys
// only for codes within MARGIN of the fp32 min (|key32-key64| <= ~5e-4).
__global__ __launch_bounds__(256) void k3_recheck(
    const float* __restrict__ x, const float* __restrict__ cb,
    const double* __restrict__ cnd, const float* __restrict__ cnf,
    int* __restrict__ bestIdx,
    const int* __restrict__ flagCount, const int* __restrict__ flagList,
    float* __restrict__ outIdx) {
  __shared__ float xs[64];
  __shared__ float rmin[256];
  __shared__ double dk[256];
  __shared__ int    di[256];
  const int tid = threadIdx.x;
  const int cnt = *flagCount;

  for (int jj = blockIdx.x; jj < cnt; jj += gridDim.x) {
    const int row = flagList[jj];
    if (tid < 16)
      reinterpret_cast<float4*>(xs)[tid] =
          reinterpret_cast<const float4*>(x + (long)row * Hn)[tid];
    __syncthreads();

    float key32[4];
#pragma unroll
    for (int cc = 0; cc < 4; ++cc) {
      const int v = cc * 256 + tid;
      const float4* c4 = reinterpret_cast<const float4*>(cb + v * Hn);
      float d0 = 0, d1 = 0, d2 = 0, d3 = 0;
#pragma unroll
      for (int k = 0; k < 16; ++k) {
        float4 f = c4[k];
        d0 = fmaf(f.x, xs[4 * k + 0], d0);
        d1 = fmaf(f.y, xs[4 * k + 1], d1);
        d2 = fmaf(f.z, xs[4 * k + 2], d2);
        d3 = fmaf(f.w, xs[4 * k + 3], d3);
      }
      key32[cc] = cnf[v] - 2.0f * ((d0 + d1) + (d2 + d3));
    }

    float m = fminf(fminf(key32[0], key32[1]), fminf(key32[2], key32[3]));
    rmin[tid] = m;
    __syncthreads();
    for (int s = 128; s > 0; s >>= 1) {
      if (tid < s) rmin[tid] = fminf(rmin[tid], rmin[tid + s]);
      __syncthreads();
    }
    const float m1 = rmin[0];

    double bk = 1e300;
    int bidx = 0x7FFFFFFF;
#pragma unroll
    for (int cc = 0; cc < 4; ++cc) {
      if (key32[cc] <= m1 + MARGIN) {
        const int v = cc * 256 + tid;
        const float4* c4 = reinterpret_cast<const float4*>(cb + v * Hn);
        double a0 = 0, a1 = 0, a2 = 0, a3 = 0;
#pragma unroll
        for (int k = 0; k < 16; ++k) {
          float4 f = c4[k];
          a0 += (double)f.x * (double)xs[4 * k + 0];
          a1 += (double)f.y * (double)xs[4 * k + 1];
          a2 += (double)f.z * (double)xs[4 * k + 2];
          a3 += (double)f.w * (double)xs[4 * k + 3];
        }
        double key = cnd[v] - 2.0 * ((a0 + a1) + (a2 + a3));
        if (key < bk || (key == bk && v < bidx)) { bk = key; bidx = v; }
      }
    }
    dk[tid] = bk; di[tid] = bidx;
    __syncthreads();
    for (int s = 128; s > 0; s >>= 1) {
      if (tid < s) {
        if (dk[tid + s] < dk[tid] ||
            (dk[tid + s] == dk[tid] && di[tid + s] < di[tid])) {
          dk[tid] = dk[tid + s]; di[tid] = di[tid + s];
        }
      }
      __syncthreads();
    }
    if (tid == 0) {
      bestIdx[row] = di[0];
      outIdx[row] = (float)di[0];
    }
    __syncthreads();
  }
}

// Gather quantized + fp64 loss partials (wave-shuffle reduce, barrier-light).
__global__ __launch_bounds__(256) void k4_gather(
    const float* __restrict__ x, const float* __restrict__ cb,
    const int* __restrict__ bestIdx, float* __restrict__ out,
    double* __restrict__ partials) {
  __shared__ double wsum[4];
  const int tid = threadIdx.x;
  double acc = 0;
#pragma unroll
  for (int q = 0; q < 4; ++q) {
    const int t = blockIdx.x * 1024 + q * 256 + tid;   // float4 index
    const int i = t * 4;
    const int row = i >> 6;
    const int h4 = (i & 63) >> 2;
    const int idx = bestIdx[row];
    float4 qv = reinterpret_cast<const float4*>(cb)[idx * 16 + h4];
    float4 xv = reinterpret_cast<const float4*>(x)[t];
    reinterpret_cast<float4*>(out)[t] = qv;
    double dx = (double)qv.x - (double)xv.x;
    double dy = (double)qv.y - (double)xv.y;
    double dz = (double)qv.z - (double)xv.z;
    double dw = (double)qv.w - (double)xv.w;
    acc += dx * dx + dy * dy + dz * dz + dw * dw;
  }
#pragma unroll
  for (int m = 32; m > 0; m >>= 1) acc += __shfl_down(acc, m);  // fixed order
  if ((tid & 63) == 0) wsum[tid >> 6] = acc;
  __syncthreads();
  if (tid == 0) partials[blockIdx.x] = (wsum[0] + wsum[1]) + (wsum[2] + wsum[3]);
}

__global__ __launch_bounds__(256) void k6_loss(const double* __restrict__ partials,
                                               float* __restrict__ out) {
  __shared__ double red[256];
  double a = 0;
  for (int k = threadIdx.x; k < 1024; k += 256) a += partials[k];  // fixed order
  red[threadIdx.x] = a;
  __syncthreads();
  for (int s = 128; s > 0; s >>= 1) {
    if (threadIdx.x < s) red[threadIdx.x] += red[threadIdx.x + s];
    __syncthreads();
  }
  if (threadIdx.x == 0)
    out[QSZ] = (float)(1.25 * red[0] / (double)QSZ);
}

extern "C" void kernel_launch(void* const* d_in, const int* in_sizes, int n_in,
                              void* d_out, int out_size, void* d_ws, size_t ws_size,
                              hipStream_t stream) {
  const float* x  = (const float*)d_in[0];
  const float* cb = (const float*)d_in[1];
  float* out = (float*)d_out;
  char* ws = (char*)d_ws;

  double* cnd      = (double*)(ws + 0);
  double* partials = (double*)(ws + 8192);
  float*  cnf      = (float*) (ws + 40960);
  int*    bestIdx  = (int*)   (ws + 45056);
  int*    flagCnt  = (int*)   (ws + 307200);
  int*    flagList = (int*)   (ws + 307208);
  unsigned short* cwT = (unsigned short*)(ws + 573440);

  float* outIdx = out + QSZ + 1;

  kC        <<<16,   256, 0, stream>>>(cb, cwT, cnd, cnf, flagCnt);
  kMF       <<<2048, 256, 0, stream>>>(x, cwT, cnf, bestIdx, flagCnt, flagList, outIdx);
  k3_recheck<<<1024, 256, 0, stream>>>(x, cb, cnd, cnf, bestIdx, flagCnt, flagList, outIdx);
  k4_gather <<<1024, 256, 0, stream>>>(x, cb, bestIdx, out, partials);
  k6_loss   <<<1,    256, 0, stream>>>(partials, out);
}

// Round 10
// 173.049 us; speedup vs baseline: 1.3288x; 1.3288x over previous
//
#include <hip/hip_runtime.h>

// VectorQuantizer: x[128,512,64] f32, codebook[1024,64] f32
// outputs (flat in d_out, float32): quantized[4194304], loss[1], indices[65536]
//
// R10: kMF restructured per Little's-law analysis of R7 (79us = 512MB L2
// demand / ~3B/cyc/SIMD in flight) and R9's lesson (global_load_lds bypasses
// L2 reuse: FETCH 9MB->426MB). Each wave owns ONE 16-row M-tile and sweeps
// ALL 1024 codes: block = 4 waves = 64 rows, grid 1024 -> L2 demand 256MB;
// no LDS, no barriers, no cross-wave merge. Tiny state (A=16, top2=12 VGPR)
// leaves room for a rolled ping-pong 2-tile B prefetch (named BA/BB, static
// indices) -> ~2.3KB in flight/SIMD -> memory side ~11us.
// Exactness: fp32 top-2 gap screen (err <= ~2.4e-2 < TAU=0.05); flagged rows
// -> k3 fp32-exact sweep + selective fp64 -> argmin fp64-exact. Loss fp64,
// fixed order (deterministic).

typedef __attribute__((ext_vector_type(8))) short bf16x8;
typedef __attribute__((ext_vector_type(4))) float f32x4;
typedef __attribute__((ext_vector_type(8))) unsigned short u16x8;

static constexpr int Vn    = 1024;
static constexpr int Hn    = 64;
static constexpr int Nrows = 128 * 512;          // 65536
static constexpr int QSZ   = Nrows * Hn;         // 4194304
#define TAU 0.05f
#define MARGIN 4e-3f

__device__ inline unsigned short f2bf(float f) {         // RNE fp32->bf16
  unsigned u = __float_as_uint(f);
  return (unsigned short)((u + 0x7fffu + ((u >> 16) & 1u)) >> 16);
}
__device__ inline float bf2f(unsigned short h) {
  return __uint_as_float(((unsigned)h) << 16);
}

// ---- ws layout (bytes) ----
// 0      : double cnormd[1024]       (8192)
// 8192   : double partials[1024]     (8192; region reserves 32768)
// 40960  : float  cnormf[1024]       (4096)
// 45056  : int    bestIdx[65536]     (262144)
// 307200 : int    flagCount          (8)
// 307208 : int    flagList[65536]    (262144)
// 573440 : ushort cw[1024*128]       (262144)   [ch(64)|cl(64)] per code

// Codebook prep: thread = (code v, 16-elem segment). Coalesced float4 loads,
// 4-lane shfl_xor fp64 norm reduction, bf16 hi/lo split stores.
__global__ __launch_bounds__(256) void kC(
    const float* __restrict__ cb, unsigned short* __restrict__ cw,
    double* __restrict__ cnd, float* __restrict__ cnf,
    int* __restrict__ flagCount) {
  const int t = blockIdx.x * 256 + threadIdx.x;  // 4096 threads
  if (t == 0) *flagCount = 0;
  const int v = t >> 2, seg = t & 3;
  const float4* src = reinterpret_cast<const float4*>(cb + v * Hn + seg * 16);
  float vals[16];
  double s = 0;
#pragma unroll
  for (int q = 0; q < 4; ++q) {
    float4 f = src[q];
    vals[q * 4 + 0] = f.x; vals[q * 4 + 1] = f.y;
    vals[q * 4 + 2] = f.z; vals[q * 4 + 3] = f.w;
    s += (double)f.x * f.x + (double)f.y * f.y +
         (double)f.z * f.z + (double)f.w * f.w;
  }
  s += __shfl_xor(s, 1);                         // 4-lane group reduce
  s += __shfl_xor(s, 2);
  if (seg == 0) { cnd[v] = s; cnf[v] = (float)s; }
  u16x8 hv, hv1, lv0, lv1;
#pragma unroll
  for (int j = 0; j < 8; ++j) {
    unsigned short h = f2bf(vals[j]);
    hv[j] = h; lv0[j] = f2bf(vals[j] - bf2f(h));
    unsigned short h2 = f2bf(vals[8 + j]);
    hv1[j] = h2; lv1[j] = f2bf(vals[8 + j] - bf2f(h2));
  }
  u16x8* dh = (u16x8*)(cw + v * 128 + seg * 16);
  dh[0] = hv; dh[1] = hv1;
  u16x8* dl = (u16x8*)(cw + v * 128 + 64 + seg * 16);
  dl[0] = lv0; dl[1] = lv1;
}

// Fused MFMA screen + argmin. Wave-autonomous: each wave owns 16 rows and
// sweeps all 1024 codes as 64 tiles of 16, ping-pong 2-tile B prefetch.
// Per tile: K=192 via 6 MFMA ((-2xh).ch + (-2xh).cl + (-2xl).ch), C-init =
// ||c||^2 -> acc = key. C frag: col=lane&15, row=4*(lane>>4)+reg (verified
// R4-R8). No LDS, no barriers.
__global__ __launch_bounds__(256, 4) void kMF(
    const float* __restrict__ x, const unsigned short* __restrict__ cw,
    const float* __restrict__ cnf, int* __restrict__ bestIdx,
    int* __restrict__ flagCount, int* __restrict__ flagList,
    float* __restrict__ outIdx) {
  const int tid = threadIdx.x;
  const int lane = tid & 63;
  const int w = tid >> 6;
  const int l15 = lane & 15, g = lane >> 4;
  const int rowBase = blockIdx.x * 64 + w * 16;  // this wave's 16 rows

  // A fragments {h0,h1,l0,l1} of (-2x) for rows rowBase..rowBase+15.
  bf16x8 A0, A1, A2, A3;
  {
    const float* xr = x + (long)(rowBase + l15) * Hn + g * 8;
    float4 fa0 = *(const float4*)(xr + 0);
    float4 fa1 = *(const float4*)(xr + 4);
    float4 fb0 = *(const float4*)(xr + 32);
    float4 fb1 = *(const float4*)(xr + 36);
    float va[8] = {fa0.x, fa0.y, fa0.z, fa0.w, fa1.x, fa1.y, fa1.z, fa1.w};
    float vb[8] = {fb0.x, fb0.y, fb0.z, fb0.w, fb1.x, fb1.y, fb1.z, fb1.w};
#pragma unroll
    for (int j = 0; j < 8; ++j) {
      float sa = -2.0f * va[j];
      unsigned short h = f2bf(sa);
      A0[j] = (short)h;
      A2[j] = (short)f2bf(sa - bf2f(h));
      float sb = -2.0f * vb[j];
      unsigned short h2 = f2bf(sb);
      A1[j] = (short)h2;
      A3[j] = (short)f2bf(sb - bf2f(h2));
    }
  }

  float b1[4], b2[4];
  int   bi[4];
#pragma unroll
  for (int r = 0; r < 4; ++r) { b1[r] = 3.4e38f; b2[r] = 3.4e38f; bi[r] = 0; }

#define LOADB(B0v, B1v, B2v, B3v, CNv, ct_)                                  \
  {                                                                          \
    const unsigned short* p_ = cw + (ct_) * 2048 + l15 * 128 + g * 8;        \
    B0v = *(const bf16x8*)(p_ + 0);                                          \
    B1v = *(const bf16x8*)(p_ + 32);                                         \
    B2v = *(const bf16x8*)(p_ + 64);                                         \
    B3v = *(const bf16x8*)(p_ + 96);                                         \
    CNv = cnf[(ct_) * 16 + l15];                                             \
  }

#define COMPUTE(B0v, B1v, B2v, B3v, CNv, ct_)                                \
  {                                                                          \
    f32x4 acc = {CNv, CNv, CNv, CNv};                                        \
    acc = __builtin_amdgcn_mfma_f32_16x16x32_bf16(A0, B0v, acc, 0, 0, 0);    \
    acc = __builtin_amdgcn_mfma_f32_16x16x32_bf16(A1, B1v, acc, 0, 0, 0);    \
    acc = __builtin_amdgcn_mfma_f32_16x16x32_bf16(A0, B2v, acc, 0, 0, 0);    \
    acc = __builtin_amdgcn_mfma_f32_16x16x32_bf16(A1, B3v, acc, 0, 0, 0);    \
    acc = __builtin_amdgcn_mfma_f32_16x16x32_bf16(A2, B0v, acc, 0, 0, 0);    \
    acc = __builtin_amdgcn_mfma_f32_16x16x32_bf16(A3, B1v, acc, 0, 0, 0);    \
    const int v_ = (ct_) * 16 + l15;                                         \
    _Pragma("unroll")                                                        \
    for (int r = 0; r < 4; ++r) {                                            \
      float key = acc[r];                                                    \
      bool lt = key < b1[r];                                                 \
      b2[r] = __builtin_amdgcn_fmed3f(key, b1[r], b2[r]);                    \
      b1[r] = fminf(b1[r], key);                                             \
      bi[r] = lt ? v_ : bi[r];                                               \
    }                                                                        \
  }

  bf16x8 BA0, BA1, BA2, BA3, BB0, BB1, BB2, BB3;
  float cnA, cnB;
  LOADB(BA0, BA1, BA2, BA3, cnA, 0);
  for (int ct = 0; ct < 64; ct += 2) {
    LOADB(BB0, BB1, BB2, BB3, cnB, ct + 1);      // prefetch odd tile
    COMPUTE(BA0, BA1, BA2, BA3, cnA, ct);        // compute even tile
    if (ct < 62)
      LOADB(BA0, BA1, BA2, BA3, cnA, ct + 2);    // prefetch next even tile
    COMPUTE(BB0, BB1, BB2, BB3, cnB, ct + 1);    // compute odd tile
  }
#undef LOADB
#undef COMPUTE

  // Merge top-2 across the 16 lanes holding each row (cols 0..15 subsets).
#pragma unroll
  for (int r = 0; r < 4; ++r) {
    float B1r = b1[r], B2r = b2[r];
    int Ir = bi[r];
#pragma unroll
    for (int m = 1; m < 16; m <<= 1) {
      float o1 = __shfl_xor(B1r, m), o2 = __shfl_xor(B2r, m);
      int oi = __shfl_xor(Ir, m);
      float worse = fmaxf(B1r, o1);
      B2r = fminf(fminf(B2r, o2), worse);
      bool take = (o1 < B1r) || (o1 == B1r && oi < Ir);
      B1r = take ? o1 : B1r;
      Ir  = take ? oi : Ir;
    }
    b1[r] = B1r; b2[r] = B2r; bi[r] = Ir;
  }

  // Writers: lane with l15==r publishes row rowBase + 4g + r.
#pragma unroll
  for (int r = 0; r < 4; ++r)
    if (l15 == r) {
      const int row = rowBase + 4 * g + r;
      bestIdx[row] = bi[r];
      outIdx[row] = (float)bi[r];
      if (b2[r] - b1[r] <= TAU) {
        int slot = atomicAdd(flagCount, 1);
        flagList[slot] = row;                    // order-independent use
      }
    }
}

// Recheck flagged rows: exact-fp32 sweep of all 1024 codes, then fp64 keys
// only for codes within MARGIN of the fp32 min (|key32-key64| <= ~5e-4).
__global__ __launch_bounds__(256) void k3_recheck(
    const float* __restrict__ x, const float* __restrict__ cb,
    const double* __restrict__ cnd, const float* __restrict__ cnf,
    int* __restrict__ bestIdx,
    const int* __restrict__ flagCount, const int* __restrict__ flagList,
    float* __restrict__ outIdx) {
  __shared__ float xs[64];
  __shared__ float rmin[256];
  __shared__ double dk[256];
  __shared__ int    di[256];
  const int tid = threadIdx.x;
  const int cnt = *flagCount;

  for (int jj = blockIdx.x; jj < cnt; jj += gridDim.x) {
    const int row = flagList[jj];
    if (tid < 16)
      reinterpret_cast<float4*>(xs)[tid] =
          reinterpret_cast<const float4*>(x + (long)row * Hn)[tid];
    __syncthreads();

    float key32[4];
#pragma unroll
    for (int cc = 0; cc < 4; ++cc) {
      const int v = cc * 256 + tid;
      const float4* c4 = reinterpret_cast<const float4*>(cb + v * Hn);
      float d0 = 0, d1 = 0, d2 = 0, d3 = 0;
#pragma unroll
      for (int k = 0; k < 16; ++k) {
        float4 f = c4[k];
        d0 = fmaf(f.x, xs[4 * k + 0], d0);
        d1 = fmaf(f.y, xs[4 * k + 1], d1);
        d2 = fmaf(f.z, xs[4 * k + 2], d2);
        d3 = fmaf(f.w, xs[4 * k + 3], d3);
      }
      key32[cc] = cnf[v] - 2.0f * ((d0 + d1) + (d2 + d3));
    }

    float m = fminf(fminf(key32[0], key32[1]), fminf(key32[2], key32[3]));
    rmin[tid] = m;
    __syncthreads();
    for (int s = 128; s > 0; s >>= 1) {
      if (tid < s) rmin[tid] = fminf(rmin[tid], rmin[tid + s]);
      __syncthreads();
    }
    const float m1 = rmin[0];

    double bk = 1e300;
    int bidx = 0x7FFFFFFF;
#pragma unroll
    for (int cc = 0; cc < 4; ++cc) {
      if (key32[cc] <= m1 + MARGIN) {
        const int v = cc * 256 + tid;
        const float4* c4 = reinterpret_cast<const float4*>(cb + v * Hn);
        double a0 = 0, a1 = 0, a2 = 0, a3 = 0;
#pragma unroll
        for (int k = 0; k < 16; ++k) {
          float4 f = c4[k];
          a0 += (double)f.x * (double)xs[4 * k + 0];
          a1 += (double)f.y * (double)xs[4 * k + 1];
          a2 += (double)f.z * (double)xs[4 * k + 2];
          a3 += (double)f.w * (double)xs[4 * k + 3];
        }
        double key = cnd[v] - 2.0 * ((a0 + a1) + (a2 + a3));
        if (key < bk || (key == bk && v < bidx)) { bk = key; bidx = v; }
      }
    }
    dk[tid] = bk; di[tid] = bidx;
    __syncthreads();
    for (int s = 128; s > 0; s >>= 1) {
      if (tid < s) {
        if (dk[tid + s] < dk[tid] ||
            (dk[tid + s] == dk[tid] && di[tid + s] < di[tid])) {
          dk[tid] = dk[tid + s]; di[tid] = di[tid + s];
        }
      }
      __syncthreads();
    }
    if (tid == 0) {
      bestIdx[row] = di[0];
      outIdx[row] = (float)di[0];
    }
    __syncthreads();
  }
}

// Gather quantized + fp64 loss partials (wave-shuffle reduce, barrier-light).
__global__ __launch_bounds__(256) void k4_gather(
    const float* __restrict__ x, const float* __restrict__ cb,
    const int* __restrict__ bestIdx, float* __restrict__ out,
    double* __restrict__ partials) {
  __shared__ double wsum[4];
  const int tid = threadIdx.x;
  double acc = 0;
#pragma unroll
  for (int q = 0; q < 4; ++q) {
    const int t = blockIdx.x * 1024 + q * 256 + tid;   // float4 index
    const int i = t * 4;
    const int row = i >> 6;
    const int h4 = (i & 63) >> 2;
    const int idx = bestIdx[row];
    float4 qv = reinterpret_cast<const float4*>(cb)[idx * 16 + h4];
    float4 xv = reinterpret_cast<const float4*>(x)[t];
    reinterpret_cast<float4*>(out)[t] = qv;
    double dx = (double)qv.x - (double)xv.x;
    double dy = (double)qv.y - (double)xv.y;
    double dz = (double)qv.z - (double)xv.z;
    double dw = (double)qv.w - (double)xv.w;
    acc += dx * dx + dy * dy + dz * dz + dw * dw;
  }
#pragma unroll
  for (int m = 32; m > 0; m >>= 1) acc += __shfl_down(acc, m);  // fixed order
  if ((tid & 63) == 0) wsum[tid >> 6] = acc;
  __syncthreads();
  if (tid == 0) partials[blockIdx.x] = (wsum[0] + wsum[1]) + (wsum[2] + wsum[3]);
}

__global__ __launch_bounds__(256) void k6_loss(const double* __restrict__ partials,
                                               float* __restrict__ out) {
  __shared__ double red[256];
  double a = 0;
  for (int k = threadIdx.x; k < 1024; k += 256) a += partials[k];  // fixed order
  red[threadIdx.x] = a;
  __syncthreads();
  for (int s = 128; s > 0; s >>= 1) {
    if (threadIdx.x < s) red[threadIdx.x] += red[threadIdx.x + s];
    __syncthreads();
  }
  if (threadIdx.x == 0)
    out[QSZ] = (float)(1.25 * red[0] / (double)QSZ);
}

extern "C" void kernel_launch(void* const* d_in, const int* in_sizes, int n_in,
                              void* d_out, int out_size, void* d_ws, size_t ws_size,
                              hipStream_t stream) {
  const float* x  = (const float*)d_in[0];
  const float* cb = (const float*)d_in[1];
  float* out = (float*)d_out;
  char* ws = (char*)d_ws;

  double* cnd      = (double*)(ws + 0);
  double* partials = (double*)(ws + 8192);
  float*  cnf      = (float*) (ws + 40960);
  int*    bestIdx  = (int*)   (ws + 45056);
  int*    flagCnt  = (int*)   (ws + 307200);
  int*    flagList = (int*)   (ws + 307208);
  unsigned short* cw = (unsigned short*)(ws + 573440);

  float* outIdx = out + QSZ + 1;

  kC        <<<16,   256, 0, stream>>>(cb, cw, cnd, cnf, flagCnt);
  kMF       <<<1024, 256, 0, stream>>>(x, cw, cnf, bestIdx, flagCnt, flagList, outIdx);
  k3_recheck<<<1024, 256, 0, stream>>>(x, cb, cnd, cnf, bestIdx, flagCnt, flagList, outIdx);
  k4_gather <<<1024, 256, 0, stream>>>(x, cb, bestIdx, out, partials);
  k6_loss   <<<1,    256, 0, stream>>>(partials, out);
}

// Round 11
// 85.861 us; speedup vs baseline: 2.6782x; 2.0155x over previous
//
#include <hip/hip_runtime.h>

// VectorQuantizer: x[128,512,64] f32, codebook[1024,64] f32
// outputs (flat in d_out, float32): quantized[4194304], loss[1], indices[65536]
//
// R11: kMF = reg-staged LDS chunk pipeline (m151 pattern). R7/R8/R10 proved
// hipcc won't register-pipeline streams (minimizes VGPR or spills); R9 proved
// global_load_lds bypasses L2 reuse. Barriers DO pin a pipeline: per chunk,
// {issue 8x16B global loads -> regs} || {compute prev chunk from LDS} ->
// barrier -> ds_write -> barrier. 128 rows/block (L2 demand 128MB), 8 chunks
// of 128 codes, 2x32KB LDS dbuf + 4KB cnf. T2 XOR-swizzle (slot ^= (c&7)<<4)
// on the 256B/code layout: unswizzled frag reads are 16-way bank conflicts.
// Exactness: fp32 top-2 gap screen (err <= ~2.4e-2 < TAU=0.05); flagged rows
// -> k3 fp32-exact sweep + selective fp64 -> argmin fp64-exact. Loss fp64,
// fixed order (deterministic).

typedef __attribute__((ext_vector_type(8))) short bf16x8;
typedef __attribute__((ext_vector_type(4))) float f32x4;
typedef __attribute__((ext_vector_type(8))) unsigned short u16x8;

static constexpr int Vn    = 1024;
static constexpr int Hn    = 64;
static constexpr int Nrows = 128 * 512;          // 65536
static constexpr int QSZ   = Nrows * Hn;         // 4194304
#define TAU 0.05f
#define MARGIN 4e-3f

__device__ inline unsigned short f2bf(float f) {         // RNE fp32->bf16
  unsigned u = __float_as_uint(f);
  return (unsigned short)((u + 0x7fffu + ((u >> 16) & 1u)) >> 16);
}
__device__ inline float bf2f(unsigned short h) {
  return __uint_as_float(((unsigned)h) << 16);
}

// ---- ws layout (bytes) ----
// 0      : double cnormd[1024]       (8192)
// 8192   : double partials[1024]     (8192; region reserves 32768)
// 40960  : float  cnormf[1024]       (4096)
// 45056  : int    bestIdx[65536]     (262144)
// 307200 : int    flagCount          (8)
// 307208 : int    flagList[65536]    (262144)
// 573440 : ushort cw[1024*128]       (262144)   [ch(64)|cl(64)] per code

// Codebook prep: thread = (code v, 16-elem segment). Coalesced float4 loads,
// 4-lane shfl_xor fp64 norm reduction, bf16 hi/lo split stores.
__global__ __launch_bounds__(256) void kC(
    const float* __restrict__ cb, unsigned short* __restrict__ cw,
    double* __restrict__ cnd, float* __restrict__ cnf,
    int* __restrict__ flagCount) {
  const int t = blockIdx.x * 256 + threadIdx.x;  // 4096 threads
  if (t == 0) *flagCount = 0;
  const int v = t >> 2, seg = t & 3;
  const float4* src = reinterpret_cast<const float4*>(cb + v * Hn + seg * 16);
  float vals[16];
  double s = 0;
#pragma unroll
  for (int q = 0; q < 4; ++q) {
    float4 f = src[q];
    vals[q * 4 + 0] = f.x; vals[q * 4 + 1] = f.y;
    vals[q * 4 + 2] = f.z; vals[q * 4 + 3] = f.w;
    s += (double)f.x * f.x + (double)f.y * f.y +
         (double)f.z * f.z + (double)f.w * f.w;
  }
  s += __shfl_xor(s, 1);                         // 4-lane group reduce
  s += __shfl_xor(s, 2);
  if (seg == 0) { cnd[v] = s; cnf[v] = (float)s; }
  u16x8 hv, hv1, lv0, lv1;
#pragma unroll
  for (int j = 0; j < 8; ++j) {
    unsigned short h = f2bf(vals[j]);
    hv[j] = h; lv0[j] = f2bf(vals[j] - bf2f(h));
    unsigned short h2 = f2bf(vals[8 + j]);
    hv1[j] = h2; lv1[j] = f2bf(vals[8 + j] - bf2f(h2));
  }
  u16x8* dh = (u16x8*)(cw + v * 128 + seg * 16);
  dh[0] = hv; dh[1] = hv1;
  u16x8* dl = (u16x8*)(cw + v * 128 + 64 + seg * 16);
  dl[0] = lv0; dl[1] = lv1;
}

// Fused MFMA screen + argmin, LDS-chunk pipeline. Block = 4 waves, each wave
// owns 32 rows (2 row-tiles) and sweeps ALL 1024 codes; codebook streamed as
// 8 chunks of 128 codes through a double-buffered 32KB LDS tile shared by
// all waves. Per tile: K=192 via 6 MFMA ((-2xh).ch + (-2xh).cl + (-2xl).ch),
// C-init = ||c||^2 -> acc = key. C frag: col=lane&15, row=4*(lane>>4)+reg.
__global__ __launch_bounds__(256, 2) void kMF(
    const float* __restrict__ x, const unsigned short* __restrict__ cw,
    const float* __restrict__ cnf, int* __restrict__ bestIdx,
    int* __restrict__ flagCount, int* __restrict__ flagList,
    float* __restrict__ outIdx) {
  __shared__ __align__(16) char buf[2][32768];   // 128 codes x 256B, swizzled
  __shared__ __align__(16) float ldsCnf[1024];

  const int tid = threadIdx.x;
  const int lane = tid & 63;
  const int w = tid >> 6;
  const int l15 = lane & 15, g = lane >> 4;
  const int rowBase = blockIdx.x * 128 + w * 32; // this wave's 32 rows
  const char* cwb = (const char*)cw;

  // ---- A fragments: 2 row-tiles x {h0,h1,l0,l1} of (-2x) ----
  bf16x8 A[2][4];
#pragma unroll
  for (int rt = 0; rt < 2; ++rt) {
    const float* xr = x + (long)(rowBase + rt * 16 + l15) * Hn + g * 8;
    float4 fa0 = *(const float4*)(xr + 0);
    float4 fa1 = *(const float4*)(xr + 4);
    float4 fb0 = *(const float4*)(xr + 32);
    float4 fb1 = *(const float4*)(xr + 36);
    float va[8] = {fa0.x, fa0.y, fa0.z, fa0.w, fa1.x, fa1.y, fa1.z, fa1.w};
    float vb[8] = {fb0.x, fb0.y, fb0.z, fb0.w, fb1.x, fb1.y, fb1.z, fb1.w};
    bf16x8 h0, h1, l0, l1;
#pragma unroll
    for (int j = 0; j < 8; ++j) {
      float sa = -2.0f * va[j];
      unsigned short h = f2bf(sa);
      h0[j] = (short)h;
      l0[j] = (short)f2bf(sa - bf2f(h));
      float sb = -2.0f * vb[j];
      unsigned short h2 = f2bf(sb);
      h1[j] = (short)h2;
      l1[j] = (short)f2bf(sb - bf2f(h2));
    }
    A[rt][0] = h0; A[rt][1] = h1; A[rt][2] = l0; A[rt][3] = l1;
  }

  float b1[2][4], b2[2][4];
  int   bi[2][4];
#pragma unroll
  for (int rt = 0; rt < 2; ++rt)
#pragma unroll
    for (int r = 0; r < 4; ++r) { b1[rt][r] = 3.4e38f; b2[rt][r] = 3.4e38f; bi[rt][r] = 0; }

// swizzled LDS byte offset for 16B unit u of local code c (T2 pattern)
#define SWZ(c_, u_) ((c_) * 256 + (((u_) * 16) ^ (((c_) & 7) << 4)))

  // ---- prologue: stage chunk 0 + cnf ----
  {
    const char* gp = cwb + tid * 128;            // chunk 0
    float4 s0 = *(const float4*)(gp + 0),   s1 = *(const float4*)(gp + 16);
    float4 s2 = *(const float4*)(gp + 32),  s3 = *(const float4*)(gp + 48);
    float4 s4 = *(const float4*)(gp + 64),  s5 = *(const float4*)(gp + 80);
    float4 s6 = *(const float4*)(gp + 96),  s7 = *(const float4*)(gp + 112);
    float4 cf = reinterpret_cast<const float4*>(cnf)[tid];
#pragma unroll
    for (int i = 0; i < 8; ++i) {
      const int unit = tid * 8 + i;
      const int c = unit >> 4, u = unit & 15;
      float4 sv = (i == 0) ? s0 : (i == 1) ? s1 : (i == 2) ? s2 : (i == 3) ? s3
                : (i == 4) ? s4 : (i == 5) ? s5 : (i == 6) ? s6 : s7;
      *(float4*)(&buf[0][SWZ(c, u)]) = sv;
    }
    reinterpret_cast<float4*>(ldsCnf)[tid] = cf;
  }
  __syncthreads();

  // ---- main loop: load(next)->regs || compute(cur) ; bar ; ds_write ; bar --
  for (int ch = 0; ch < 8; ++ch) {
    float4 s0, s1, s2, s3, s4, s5, s6, s7;
    if (ch < 7) {                                // issue next-chunk loads NOW
      const char* gp = cwb + (ch + 1) * 32768 + tid * 128;
      s0 = *(const float4*)(gp + 0);   s1 = *(const float4*)(gp + 16);
      s2 = *(const float4*)(gp + 32);  s3 = *(const float4*)(gp + 48);
      s4 = *(const float4*)(gp + 64);  s5 = *(const float4*)(gp + 80);
      s6 = *(const float4*)(gp + 96);  s7 = *(const float4*)(gp + 112);
    }

    const char* Bb = buf[ch & 1];
#pragma unroll
    for (int tt = 0; tt < 8; ++tt) {
      const int cl = tt * 16 + l15;              // local code in chunk
      const char* cbase = Bb + cl * 256;
      const int sw = (cl & 7) << 4;
      bf16x8 B0 = *(const bf16x8*)(cbase + ((16 * g) ^ sw));        // ch lo-K
      bf16x8 B1 = *(const bf16x8*)(cbase + ((64 + 16 * g) ^ sw));   // ch hi-K
      bf16x8 B2 = *(const bf16x8*)(cbase + ((128 + 16 * g) ^ sw));  // cl lo-K
      bf16x8 B3 = *(const bf16x8*)(cbase + ((192 + 16 * g) ^ sw));  // cl hi-K
      const int v = ch * 128 + cl;
      const float cnfv = ldsCnf[v];
#pragma unroll
      for (int rt = 0; rt < 2; ++rt) {
        f32x4 acc = {cnfv, cnfv, cnfv, cnfv};    // C-init = ||c||^2
        acc = __builtin_amdgcn_mfma_f32_16x16x32_bf16(A[rt][0], B0, acc, 0, 0, 0);
        acc = __builtin_amdgcn_mfma_f32_16x16x32_bf16(A[rt][1], B1, acc, 0, 0, 0);
        acc = __builtin_amdgcn_mfma_f32_16x16x32_bf16(A[rt][0], B2, acc, 0, 0, 0);
        acc = __builtin_amdgcn_mfma_f32_16x16x32_bf16(A[rt][1], B3, acc, 0, 0, 0);
        acc = __builtin_amdgcn_mfma_f32_16x16x32_bf16(A[rt][2], B0, acc, 0, 0, 0);
        acc = __builtin_amdgcn_mfma_f32_16x16x32_bf16(A[rt][3], B1, acc, 0, 0, 0);
#pragma unroll
        for (int r = 0; r < 4; ++r) {
          float key = acc[r];                    // = ||c||^2 - 2 x.c
          bool lt = key < b1[rt][r];
          b2[rt][r] = __builtin_amdgcn_fmed3f(key, b1[rt][r], b2[rt][r]);
          b1[rt][r] = fminf(b1[rt][r], key);
          bi[rt][r] = lt ? v : bi[rt][r];
        }
      }
    }
    __syncthreads();                             // all waves done with buf[(ch+1)&1]
    if (ch < 7) {
#pragma unroll
      for (int i = 0; i < 8; ++i) {
        const int unit = tid * 8 + i;
        const int c = unit >> 4, u = unit & 15;
        float4 sv = (i == 0) ? s0 : (i == 1) ? s1 : (i == 2) ? s2 : (i == 3) ? s3
                  : (i == 4) ? s4 : (i == 5) ? s5 : (i == 6) ? s6 : s7;
        *(float4*)(&buf[(ch + 1) & 1][SWZ(c, u)]) = sv;
      }
    }
    __syncthreads();                             // next chunk visible
  }
#undef SWZ

  // ---- merge top-2 across the 16 lanes holding each row ----
#pragma unroll
  for (int rt = 0; rt < 2; ++rt)
#pragma unroll
    for (int r = 0; r < 4; ++r) {
      float B1r = b1[rt][r], B2r = b2[rt][r];
      int Ir = bi[rt][r];
#pragma unroll
      for (int m = 1; m < 16; m <<= 1) {
        float o1 = __shfl_xor(B1r, m), o2 = __shfl_xor(B2r, m);
        int oi = __shfl_xor(Ir, m);
        float worse = fmaxf(B1r, o1);
        B2r = fminf(fminf(B2r, o2), worse);
        bool take = (o1 < B1r) || (o1 == B1r && oi < Ir);
        B1r = take ? o1 : B1r;
        Ir  = take ? oi : Ir;
      }
      b1[rt][r] = B1r; b2[rt][r] = B2r; bi[rt][r] = Ir;
    }

  // Writers: lane with l15==r publishes row rowBase + rt*16 + 4g + r.
#pragma unroll
  for (int rt = 0; rt < 2; ++rt)
#pragma unroll
    for (int r = 0; r < 4; ++r)
      if (l15 == r) {
        const int row = rowBase + rt * 16 + 4 * g + r;
        bestIdx[row] = bi[rt][r];
        outIdx[row] = (float)bi[rt][r];
        if (b2[rt][r] - b1[rt][r] <= TAU) {
          int slot = atomicAdd(flagCount, 1);
          flagList[slot] = row;                  // order-independent use
        }
      }
}

// Recheck flagged rows: exact-fp32 sweep of all 1024 codes, then fp64 keys
// only for codes within MARGIN of the fp32 min (|key32-key64| <= ~5e-4).
__global__ __launch_bounds__(256) void k3_recheck(
    const float* __restrict__ x, const float* __restrict__ cb,
    const double* __restrict__ cnd, const float* __restrict__ cnf,
    int* __restrict__ bestIdx,
    const int* __restrict__ flagCount, const int* __restrict__ flagList,
    float* __restrict__ outIdx) {
  __shared__ float xs[64];
  __shared__ float rmin[256];
  __shared__ double dk[256];
  __shared__ int    di[256];
  const int tid = threadIdx.x;
  const int cnt = *flagCount;

  for (int jj = blockIdx.x; jj < cnt; jj += gridDim.x) {
    const int row = flagList[jj];
    if (tid < 16)
      reinterpret_cast<float4*>(xs)[tid] =
          reinterpret_cast<const float4*>(x + (long)row * Hn)[tid];
    __syncthreads();

    float key32[4];
#pragma unroll
    for (int cc = 0; cc < 4; ++cc) {
      const int v = cc * 256 + tid;
      const float4* c4 = reinterpret_cast<const float4*>(cb + v * Hn);
      float d0 = 0, d1 = 0, d2 = 0, d3 = 0;
#pragma unroll
      for (int k = 0; k < 16; ++k) {
        float4 f = c4[k];
        d0 = fmaf(f.x, xs[4 * k + 0], d0);
        d1 = fmaf(f.y, xs[4 * k + 1], d1);
        d2 = fmaf(f.z, xs[4 * k + 2], d2);
        d3 = fmaf(f.w, xs[4 * k + 3], d3);
      }
      key32[cc] = cnf[v] - 2.0f * ((d0 + d1) + (d2 + d3));
    }

    float m = fminf(fminf(key32[0], key32[1]), fminf(key32[2], key32[3]));
    rmin[tid] = m;
    __syncthreads();
    for (int s = 128; s > 0; s >>= 1) {
      if (tid < s) rmin[tid] = fminf(rmin[tid], rmin[tid + s]);
      __syncthreads();
    }
    const float m1 = rmin[0];

    double bk = 1e300;
    int bidx = 0x7FFFFFFF;
#pragma unroll
    for (int cc = 0; cc < 4; ++cc) {
      if (key32[cc] <= m1 + MARGIN) {
        const int v = cc * 256 + tid;
        const float4* c4 = reinterpret_cast<const float4*>(cb + v * Hn);
        double a0 = 0, a1 = 0, a2 = 0, a3 = 0;
#pragma unroll
        for (int k = 0; k < 16; ++k) {
          float4 f = c4[k];
          a0 += (double)f.x * (double)xs[4 * k + 0];
          a1 += (double)f.y * (double)xs[4 * k + 1];
          a2 += (double)f.z * (double)xs[4 * k + 2];
          a3 += (double)f.w * (double)xs[4 * k + 3];
        }
        double key = cnd[v] - 2.0 * ((a0 + a1) + (a2 + a3));
        if (key < bk || (key == bk && v < bidx)) { bk = key; bidx = v; }
      }
    }
    dk[tid] = bk; di[tid] = bidx;
    __syncthreads();
    for (int s = 128; s > 0; s >>= 1) {
      if (tid < s) {
        if (dk[tid + s] < dk[tid] ||
            (dk[tid + s] == dk[tid] && di[tid + s] < di[tid])) {
          dk[tid] = dk[tid + s]; di[tid] = di[tid + s];
        }
      }
      __syncthreads();
    }
    if (tid == 0) {
      bestIdx[row] = di[0];
      outIdx[row] = (float)di[0];
    }
    __syncthreads();
  }
}

// Gather quantized + fp64 loss partials (wave-shuffle reduce, barrier-light).
__global__ __launch_bounds__(256) void k4_gather(
    const float* __restrict__ x, const float* __restrict__ cb,
    const int* __restrict__ bestIdx, float* __restrict__ out,
    double* __restrict__ partials) {
  __shared__ double wsum[4];
  const int tid = threadIdx.x;
  double acc = 0;
#pragma unroll
  for (int q = 0; q < 4; ++q) {
    const int t = blockIdx.x * 1024 + q * 256 + tid;   // float4 index
    const int i = t * 4;
    const int row = i >> 6;
    const int h4 = (i & 63) >> 2;
    const int idx = bestIdx[row];
    float4 qv = reinterpret_cast<const float4*>(cb)[idx * 16 + h4];
    float4 xv = reinterpret_cast<const float4*>(x)[t];
    reinterpret_cast<float4*>(out)[t] = qv;
    double dx = (double)qv.x - (double)xv.x;
    double dy = (double)qv.y - (double)xv.y;
    double dz = (double)qv.z - (double)xv.z;
    double dw = (double)qv.w - (double)xv.w;
    acc += dx * dx + dy * dy + dz * dz + dw * dw;
  }
#pragma unroll
  for (int m = 32; m > 0; m >>= 1) acc += __shfl_down(acc, m);  // fixed order
  if ((tid & 63) == 0) wsum[tid >> 6] = acc;
  __syncthreads();
  if (tid == 0) partials[blockIdx.x] = (wsum[0] + wsum[1]) + (wsum[2] + wsum[3]);
}

__global__ __launch_bounds__(256) void k6_loss(const double* __restrict__ partials,
                                               float* __restrict__ out) {
  __shared__ double red[256];
  double a = 0;
  for (int k = threadIdx.x; k < 1024; k += 256) a += partials[k];  // fixed order
  red[threadIdx.x] = a;
  __syncthreads();
  for (int s = 128; s > 0; s >>= 1) {
    if (threadIdx.x < s) red[threadIdx.x] += red[threadIdx.x + s];
    __syncthreads();
  }
  if (threadIdx.x == 0)
    out[QSZ] = (float)(1.25 * red[0] / (double)QSZ);
}

extern "C" void kernel_launch(void* const* d_in, const int* in_sizes, int n_in,
                              void* d_out, int out_size, void* d_ws, size_t ws_size,
                              hipStream_t stream) {
  const float* x  = (const float*)d_in[0];
  const float* cb = (const float*)d_in[1];
  float* out = (float*)d_out;
  char* ws = (char*)d_ws;

  double* cnd      = (double*)(ws + 0);
  double* partials = (double*)(ws + 8192);
  float*  cnf      = (float*) (ws + 40960);
  int*    bestIdx  = (int*)   (ws + 45056);
  int*    flagCnt  = (int*)   (ws + 307200);
  int*    flagList = (int*)   (ws + 307208);
  unsigned short* cw = (unsigned short*)(ws + 573440);

  float* outIdx = out + QSZ + 1;

  kC        <<<16,   256, 0, stream>>>(cb, cw, cnd, cnf, flagCnt);
  kMF       <<<512,  256, 0, stream>>>(x, cw, cnf, bestIdx, flagCnt, flagList, outIdx);
  k3_recheck<<<512,  256, 0, stream>>>(x, cb, cnd, cnf, bestIdx, flagCnt, flagList, outIdx);
  k4_gather <<<1024, 256, 0, stream>>>(x, cb, bestIdx, out, partials);
  k6_loss   <<<1,    256, 0, stream>>>(partials, out);
}

// Round 12
// 85.327 us; speedup vs baseline: 2.6950x; 1.0063x over previous
//
#include <hip/hip_runtime.h>

// VectorQuantizer: x[128,512,64] f32, codebook[1024,64] f32
// outputs (flat in d_out, float32): quantized[4194304], loss[1], indices[65536]
//
// R12: R11's barrier-pinned reg->LDS pipeline, tuned per counters:
//  - chunk 128->64 codes: LDS 69.6KB->36.9KB -> 4 blocks/CU -> 4 waves/SIMD
//    (R11 occupancy 19%, both pipes <31% = latency residue at 2 waves/SIMD).
//  - swizzle (c&7)<<4 -> (c&15)<<4: R11's 3.15M bank conflicts were the
//    missing bit-3 (slots folded 16->8). Full 4-bit XOR is bijective per
//    16-lane phase on both ds_read (slot=u^l15) and ds_write.
// Pipeline per chunk: {4x16B global loads -> named regs} || {compute cur
// chunk from LDS} -> barrier -> ds_write -> barrier. 128 rows/block, grid
// 512 -> codebook L2 demand 128MB, FETCH stays ~9MB (L2-resident).
// Exactness: fp32 top-2 gap screen (err <= ~2.4e-2 < TAU=0.05); flagged rows
// -> k3 fp32-exact sweep + selective fp64 -> argmin fp64-exact. Loss fp64,
// fixed order (deterministic).

typedef __attribute__((ext_vector_type(8))) short bf16x8;
typedef __attribute__((ext_vector_type(4))) float f32x4;
typedef __attribute__((ext_vector_type(8))) unsigned short u16x8;

static constexpr int Vn    = 1024;
static constexpr int Hn    = 64;
static constexpr int Nrows = 128 * 512;          // 65536
static constexpr int QSZ   = Nrows * Hn;         // 4194304
#define TAU 0.05f
#define MARGIN 4e-3f

__device__ inline unsigned short f2bf(float f) {         // RNE fp32->bf16
  unsigned u = __float_as_uint(f);
  return (unsigned short)((u + 0x7fffu + ((u >> 16) & 1u)) >> 16);
}
__device__ inline float bf2f(unsigned short h) {
  return __uint_as_float(((unsigned)h) << 16);
}

// ---- ws layout (bytes) ----
// 0      : double cnormd[1024]       (8192)
// 8192   : double partials[1024]     (8192; region reserves 32768)
// 40960  : float  cnormf[1024]       (4096)
// 45056  : int    bestIdx[65536]     (262144)
// 307200 : int    flagCount          (8)
// 307208 : int    flagList[65536]    (262144)
// 573440 : ushort cw[1024*128]       (262144)   [ch(64)|cl(64)] per code

// Codebook prep: thread = (code v, 16-elem segment). Coalesced float4 loads,
// 4-lane shfl_xor fp64 norm reduction, bf16 hi/lo split stores.
__global__ __launch_bounds__(256) void kC(
    const float* __restrict__ cb, unsigned short* __restrict__ cw,
    double* __restrict__ cnd, float* __restrict__ cnf,
    int* __restrict__ flagCount) {
  const int t = blockIdx.x * 256 + threadIdx.x;  // 4096 threads
  if (t == 0) *flagCount = 0;
  const int v = t >> 2, seg = t & 3;
  const float4* src = reinterpret_cast<const float4*>(cb + v * Hn + seg * 16);
  float vals[16];
  double s = 0;
#pragma unroll
  for (int q = 0; q < 4; ++q) {
    float4 f = src[q];
    vals[q * 4 + 0] = f.x; vals[q * 4 + 1] = f.y;
    vals[q * 4 + 2] = f.z; vals[q * 4 + 3] = f.w;
    s += (double)f.x * f.x + (double)f.y * f.y +
         (double)f.z * f.z + (double)f.w * f.w;
  }
  s += __shfl_xor(s, 1);                         // 4-lane group reduce
  s += __shfl_xor(s, 2);
  if (seg == 0) { cnd[v] = s; cnf[v] = (float)s; }
  u16x8 hv, hv1, lv0, lv1;
#pragma unroll
  for (int j = 0; j < 8; ++j) {
    unsigned short h = f2bf(vals[j]);
    hv[j] = h; lv0[j] = f2bf(vals[j] - bf2f(h));
    unsigned short h2 = f2bf(vals[8 + j]);
    hv1[j] = h2; lv1[j] = f2bf(vals[8 + j] - bf2f(h2));
  }
  u16x8* dh = (u16x8*)(cw + v * 128 + seg * 16);
  dh[0] = hv; dh[1] = hv1;
  u16x8* dl = (u16x8*)(cw + v * 128 + 64 + seg * 16);
  dl[0] = lv0; dl[1] = lv1;
}

// Fused MFMA screen + argmin, LDS-chunk pipeline. Block = 4 waves, each wave
// owns 32 rows (2 row-tiles) and sweeps ALL 1024 codes; codebook streamed as
// 16 chunks of 64 codes through a double-buffered 16KB LDS tile. Per tile:
// K=192 via 6 MFMA ((-2xh).ch + (-2xh).cl + (-2xl).ch), C-init = ||c||^2 ->
// acc = key. C frag: col=lane&15, row=4*(lane>>4)+reg (verified R4-R11).
__global__ __launch_bounds__(256, 4) void kMF(
    const float* __restrict__ x, const unsigned short* __restrict__ cw,
    const float* __restrict__ cnf, int* __restrict__ bestIdx,
    int* __restrict__ flagCount, int* __restrict__ flagList,
    float* __restrict__ outIdx) {
  __shared__ __align__(16) char buf[2][16384];   // 64 codes x 256B, swizzled
  __shared__ __align__(16) float ldsCnf[1024];

  const int tid = threadIdx.x;
  const int lane = tid & 63;
  const int w = tid >> 6;
  const int l15 = lane & 15, g = lane >> 4;
  const int rowBase = blockIdx.x * 128 + w * 32; // this wave's 32 rows
  const char* cwb = (const char*)cw;

  // ---- A fragments: 2 row-tiles x {h0,h1,l0,l1} of (-2x) ----
  bf16x8 A[2][4];
#pragma unroll
  for (int rt = 0; rt < 2; ++rt) {
    const float* xr = x + (long)(rowBase + rt * 16 + l15) * Hn + g * 8;
    float4 fa0 = *(const float4*)(xr + 0);
    float4 fa1 = *(const float4*)(xr + 4);
    float4 fb0 = *(const float4*)(xr + 32);
    float4 fb1 = *(const float4*)(xr + 36);
    float va[8] = {fa0.x, fa0.y, fa0.z, fa0.w, fa1.x, fa1.y, fa1.z, fa1.w};
    float vb[8] = {fb0.x, fb0.y, fb0.z, fb0.w, fb1.x, fb1.y, fb1.z, fb1.w};
    bf16x8 h0, h1, l0, l1;
#pragma unroll
    for (int j = 0; j < 8; ++j) {
      float sa = -2.0f * va[j];
      unsigned short h = f2bf(sa);
      h0[j] = (short)h;
      l0[j] = (short)f2bf(sa - bf2f(h));
      float sb = -2.0f * vb[j];
      unsigned short h2 = f2bf(sb);
      h1[j] = (short)h2;
      l1[j] = (short)f2bf(sb - bf2f(h2));
    }
    A[rt][0] = h0; A[rt][1] = h1; A[rt][2] = l0; A[rt][3] = l1;
  }

  float b1[2][4], b2[2][4];
  int   bi[2][4];
#pragma unroll
  for (int rt = 0; rt < 2; ++rt)
#pragma unroll
    for (int r = 0; r < 4; ++r) { b1[rt][r] = 3.4e38f; b2[rt][r] = 3.4e38f; bi[rt][r] = 0; }

// swizzled LDS byte offset: full 4-bit XOR -> bijective per 16-lane phase
#define SWZ(c_, u_) ((c_) * 256 + (((u_) * 16) ^ (((c_) & 15) << 4)))

  // ---- prologue: stage chunk 0 (64 codes = 16KB; 64B/thread) + cnf ----
  {
    const char* gp = cwb + tid * 64;
    float4 s0 = *(const float4*)(gp + 0),  s1 = *(const float4*)(gp + 16);
    float4 s2 = *(const float4*)(gp + 32), s3 = *(const float4*)(gp + 48);
    float4 cf = reinterpret_cast<const float4*>(cnf)[tid];
    const int c = tid >> 2;
#pragma unroll
    for (int i = 0; i < 4; ++i) {
      const int u = 4 * (tid & 3) + i;
      float4 sv = (i == 0) ? s0 : (i == 1) ? s1 : (i == 2) ? s2 : s3;
      *(float4*)(&buf[0][SWZ(c, u)]) = sv;
    }
    reinterpret_cast<float4*>(ldsCnf)[tid] = cf;
  }
  __syncthreads();

  // ---- main loop: load(next)->regs || compute(cur) ; bar ; ds_write ; bar --
  for (int ch = 0; ch < 16; ++ch) {
    float4 s0, s1, s2, s3;
    if (ch < 15) {                               // issue next-chunk loads NOW
      const char* gp = cwb + (ch + 1) * 16384 + tid * 64;
      s0 = *(const float4*)(gp + 0);   s1 = *(const float4*)(gp + 16);
      s2 = *(const float4*)(gp + 32);  s3 = *(const float4*)(gp + 48);
    }

    const char* Bb = buf[ch & 1];
#pragma unroll
    for (int tt = 0; tt < 4; ++tt) {
      const int cl = tt * 16 + l15;              // local code in chunk
      const char* cbase = Bb + cl * 256;
      const int sw = l15 << 4;                   // (cl&15)<<4 == l15<<4
      bf16x8 B0 = *(const bf16x8*)(cbase + ((16 * g) ^ sw));        // ch lo-K
      bf16x8 B1 = *(const bf16x8*)(cbase + ((64 + 16 * g) ^ sw));   // ch hi-K
      bf16x8 B2 = *(const bf16x8*)(cbase + ((128 + 16 * g) ^ sw));  // cl lo-K
      bf16x8 B3 = *(const bf16x8*)(cbase + ((192 + 16 * g) ^ sw));  // cl hi-K
      const int v = ch * 64 + cl;
      const float cnfv = ldsCnf[v];
#pragma unroll
      for (int rt = 0; rt < 2; ++rt) {
        f32x4 acc = {cnfv, cnfv, cnfv, cnfv};    // C-init = ||c||^2
        acc = __builtin_amdgcn_mfma_f32_16x16x32_bf16(A[rt][0], B0, acc, 0, 0, 0);
        acc = __builtin_amdgcn_mfma_f32_16x16x32_bf16(A[rt][1], B1, acc, 0, 0, 0);
        acc = __builtin_amdgcn_mfma_f32_16x16x32_bf16(A[rt][0], B2, acc, 0, 0, 0);
        acc = __builtin_amdgcn_mfma_f32_16x16x32_bf16(A[rt][1], B3, acc, 0, 0, 0);
        acc = __builtin_amdgcn_mfma_f32_16x16x32_bf16(A[rt][2], B0, acc, 0, 0, 0);
        acc = __builtin_amdgcn_mfma_f32_16x16x32_bf16(A[rt][3], B1, acc, 0, 0, 0);
#pragma unroll
        for (int r = 0; r < 4; ++r) {
          float key = acc[r];                    // = ||c||^2 - 2 x.c
          bool lt = key < b1[rt][r];
          b2[rt][r] = __builtin_amdgcn_fmed3f(key, b1[rt][r], b2[rt][r]);
          b1[rt][r] = fminf(b1[rt][r], key);
          bi[rt][r] = lt ? v : bi[rt][r];
        }
      }
    }
    __syncthreads();                             // all waves done with buf[(ch+1)&1]
    if (ch < 15) {
      const int c = tid >> 2;
#pragma unroll
      for (int i = 0; i < 4; ++i) {
        const int u = 4 * (tid & 3) + i;
        float4 sv = (i == 0) ? s0 : (i == 1) ? s1 : (i == 2) ? s2 : s3;
        *(float4*)(&buf[(ch + 1) & 1][SWZ(c, u)]) = sv;
      }
    }
    __syncthreads();                             // next chunk visible
  }
#undef SWZ

  // ---- merge top-2 across the 16 lanes holding each row ----
#pragma unroll
  for (int rt = 0; rt < 2; ++rt)
#pragma unroll
    for (int r = 0; r < 4; ++r) {
      float B1r = b1[rt][r], B2r = b2[rt][r];
      int Ir = bi[rt][r];
#pragma unroll
      for (int m = 1; m < 16; m <<= 1) {
        float o1 = __shfl_xor(B1r, m), o2 = __shfl_xor(B2r, m);
        int oi = __shfl_xor(Ir, m);
        float worse = fmaxf(B1r, o1);
        B2r = fminf(fminf(B2r, o2), worse);
        bool take = (o1 < B1r) || (o1 == B1r && oi < Ir);
        B1r = take ? o1 : B1r;
        Ir  = take ? oi : Ir;
      }
      b1[rt][r] = B1r; b2[rt][r] = B2r; bi[rt][r] = Ir;
    }

  // Writers: lane with l15==r publishes row rowBase + rt*16 + 4g + r.
#pragma unroll
  for (int rt = 0; rt < 2; ++rt)
#pragma unroll
    for (int r = 0; r < 4; ++r)
      if (l15 == r) {
        const int row = rowBase + rt * 16 + 4 * g + r;
        bestIdx[row] = bi[rt][r];
        outIdx[row] = (float)bi[rt][r];
        if (b2[rt][r] - b1[rt][r] <= TAU) {
          int slot = atomicAdd(flagCount, 1);
          flagList[slot] = row;                  // order-independent use
        }
      }
}

// Recheck flagged rows: exact-fp32 sweep of all 1024 codes, then fp64 keys
// only for codes within MARGIN of the fp32 min (|key32-key64| <= ~5e-4).
__global__ __launch_bounds__(256) void k3_recheck(
    const float* __restrict__ x, const float* __restrict__ cb,
    const double* __restrict__ cnd, const float* __restrict__ cnf,
    int* __restrict__ bestIdx,
    const int* __restrict__ flagCount, const int* __restrict__ flagList,
    float* __restrict__ outIdx) {
  __shared__ float xs[64];
  __shared__ float rmin[256];
  __shared__ double dk[256];
  __shared__ int    di[256];
  const int tid = threadIdx.x;
  const int cnt = *flagCount;

  for (int jj = blockIdx.x; jj < cnt; jj += gridDim.x) {
    const int row = flagList[jj];
    if (tid < 16)
      reinterpret_cast<float4*>(xs)[tid] =
          reinterpret_cast<const float4*>(x + (long)row * Hn)[tid];
    __syncthreads();

    float key32[4];
#pragma unroll
    for (int cc = 0; cc < 4; ++cc) {
      const int v = cc * 256 + tid;
      const float4* c4 = reinterpret_cast<const float4*>(cb + v * Hn);
      float d0 = 0, d1 = 0, d2 = 0, d3 = 0;
#pragma unroll
      for (int k = 0; k < 16; ++k) {
        float4 f = c4[k];
        d0 = fmaf(f.x, xs[4 * k + 0], d0);
        d1 = fmaf(f.y, xs[4 * k + 1], d1);
        d2 = fmaf(f.z, xs[4 * k + 2], d2);
        d3 = fmaf(f.w, xs[4 * k + 3], d3);
      }
      key32[cc] = cnf[v] - 2.0f * ((d0 + d1) + (d2 + d3));
    }

    float m = fminf(fminf(key32[0], key32[1]), fminf(key32[2], key32[3]));
    rmin[tid] = m;
    __syncthreads();
    for (int s = 128; s > 0; s >>= 1) {
      if (tid < s) rmin[tid] = fminf(rmin[tid], rmin[tid + s]);
      __syncthreads();
    }
    const float m1 = rmin[0];

    double bk = 1e300;
    int bidx = 0x7FFFFFFF;
#pragma unroll
    for (int cc = 0; cc < 4; ++cc) {
      if (key32[cc] <= m1 + MARGIN) {
        const int v = cc * 256 + tid;
        const float4* c4 = reinterpret_cast<const float4*>(cb + v * Hn);
        double a0 = 0, a1 = 0, a2 = 0, a3 = 0;
#pragma unroll
        for (int k = 0; k < 16; ++k) {
          float4 f = c4[k];
          a0 += (double)f.x * (double)xs[4 * k + 0];
          a1 += (double)f.y * (double)xs[4 * k + 1];
          a2 += (double)f.z * (double)xs[4 * k + 2];
          a3 += (double)f.w * (double)xs[4 * k + 3];
        }
        double key = cnd[v] - 2.0 * ((a0 + a1) + (a2 + a3));
        if (key < bk || (key == bk && v < bidx)) { bk = key; bidx = v; }
      }
    }
    dk[tid] = bk; di[tid] = bidx;
    __syncthreads();
    for (int s = 128; s > 0; s >>= 1) {
      if (tid < s) {
        if (dk[tid + s] < dk[tid] ||
            (dk[tid + s] == dk[tid] && di[tid + s] < di[tid])) {
          dk[tid] = dk[tid + s]; di[tid] = di[tid + s];
        }
      }
      __syncthreads();
    }
    if (tid == 0) {
      bestIdx[row] = di[0];
      outIdx[row] = (float)di[0];
    }
    __syncthreads();
  }
}

// Gather quantized + fp64 loss partials (wave-shuffle reduce, barrier-light).
__global__ __launch_bounds__(256) void k4_gather(
    const float* __restrict__ x, const float* __restrict__ cb,
    const int* __restrict__ bestIdx, float* __restrict__ out,
    double* __restrict__ partials) {
  __shared__ double wsum[4];
  const int tid = threadIdx.x;
  double acc = 0;
#pragma unroll
  for (int q = 0; q < 4; ++q) {
    const int t = blockIdx.x * 1024 + q * 256 + tid;   // float4 index
    const int i = t * 4;
    const int row = i >> 6;
    const int h4 = (i & 63) >> 2;
    const int idx = bestIdx[row];
    float4 qv = reinterpret_cast<const float4*>(cb)[idx * 16 + h4];
    float4 xv = reinterpret_cast<const float4*>(x)[t];
    reinterpret_cast<float4*>(out)[t] = qv;
    double dx = (double)qv.x - (double)xv.x;
    double dy = (double)qv.y - (double)xv.y;
    double dz = (double)qv.z - (double)xv.z;
    double dw = (double)qv.w - (double)xv.w;
    acc += dx * dx + dy * dy + dz * dz + dw * dw;
  }
#pragma unroll
  for (int m = 32; m > 0; m >>= 1) acc += __shfl_down(acc, m);  // fixed order
  if ((tid & 63) == 0) wsum[tid >> 6] = acc;
  __syncthreads();
  if (tid == 0) partials[blockIdx.x] = (wsum[0] + wsum[1]) + (wsum[2] + wsum[3]);
}

__global__ __launch_bounds__(256) void k6_loss(const double* __restrict__ partials,
                                               float* __restrict__ out) {
  __shared__ double red[256];
  double a = 0;
  for (int k = threadIdx.x; k < 1024; k += 256) a += partials[k];  // fixed order
  red[threadIdx.x] = a;
  __syncthreads();
  for (int s = 128; s > 0; s >>= 1) {
    if (threadIdx.x < s) red[threadIdx.x] += red[threadIdx.x + s];
    __syncthreads();
  }
  if (threadIdx.x == 0)
    out[QSZ] = (float)(1.25 * red[0] / (double)QSZ);
}

extern "C" void kernel_launch(void* const* d_in, const int* in_sizes, int n_in,
                              void* d_out, int out_size, void* d_ws, size_t ws_size,
                              hipStream_t stream) {
  const float* x  = (const float*)d_in[0];
  const float* cb = (const float*)d_in[1];
  float* out = (float*)d_out;
  char* ws = (char*)d_ws;

  double* cnd      = (double*)(ws + 0);
  double* partials = (double*)(ws + 8192);
  float*  cnf      = (float*) (ws + 40960);
  int*    bestIdx  = (int*)   (ws + 45056);
  int*    flagCnt  = (int*)   (ws + 307200);
  int*    flagList = (int*)   (ws + 307208);
  unsigned short* cw = (unsigned short*)(ws + 573440);

  float* outIdx = out + QSZ + 1;

  kC        <<<16,   256, 0, stream>>>(cb, cw, cnd, cnf, flagCnt);
  kMF       <<<512,  256, 0, stream>>>(x, cw, cnf, bestIdx, flagCnt, flagList, outIdx);
  k3_recheck<<<512,  256, 0, stream>>>(x, cb, cnd, cnf, bestIdx, flagCnt, flagList, outIdx);
  k4_gather <<<1024, 256, 0, stream>>>(x, cb, bestIdx, out, partials);
  k6_loss   <<<1,    256, 0, stream>>>(partials, out);
}